// Round 7
// baseline (117.914 us; speedup 1.0000x reference)
//
#include <hip/hip_runtime.h>
#include <hip/hip_fp16.h>
#include <math.h>

#define N_NODES 50000
#define N_EDGES 800000
#define IN_F 128
#define OUT_F 128
#define NH 3
#define SCAN_NB ((N_NODES + 255) / 256)   // 196
#define NODE_NB ((N_NODES + 31) / 32)     // 1563
#define NCNT 128                          // counting blocks (contig edge ranges)
#define EPC (N_EDGES / NCNT)              // 6250 edges per counting block

typedef __attribute__((ext_vector_type(8))) _Float16 f16x8;
typedef __attribute__((ext_vector_type(4))) float f32x4;

// ---------------------------------------------------------------------------
// K0: weight preprocessing + zeroing sync cells and the global degree
// counters (deg[] feeds the atomic-rank counting path; stream order
// guarantees completion before K1).
// ---------------------------------------------------------------------------
__global__ __launch_bounds__(256) void weights_kernel(
    const float* __restrict__ Wq, const float* __restrict__ bq,
    const float* __restrict__ aw, const float* __restrict__ ab,
    const float* __restrict__ lw,
    _Float16* __restrict__ w2h, float* __restrict__ b2,
    _Float16* __restrict__ lwh, int* __restrict__ sync,
    int* __restrict__ deg)
{
    int t = blockIdx.x * 256 + threadIdx.x;
    if (blockIdx.x == 0 && threadIdx.x < 8) sync[threadIdx.x] = 0;
    for (int z = t; z < N_NODES; z += 72 * 256) deg[z] = 0;
    if (t < 16 * 128) {
        int prow = t >> 7;
        int i    = t & 127;
        int r = -1;                       // logical row 0..5
        if (prow < 3) r = prow;
        else if (prow >= 4 && prow < 7) r = prow - 1;
        if (r < 0) {
            w2h[prow * 128 + i] = (_Float16)0.0f;
        } else {
            int hh  = (r < 3) ? r : r - 3;
            int off = (r < 3) ? 0 : 24;
            const float* awr = aw + hh * 48 + off;
            float acc = 0.0f;
            #pragma unroll
            for (int q = 0; q < 24; q++) acc += awr[q] * Wq[q * 128 + i];
            w2h[prow * 128 + i] = (_Float16)acc;
            if (i == 0) {
                float b = 0.0f;
                #pragma unroll
                for (int q = 0; q < 24; q++) b += awr[q] * bq[q];
                if (r >= 3) b += ab[hh];
                b2[r] = b;
            }
        }
    }
    int u = t - 16 * 128;
    if (u >= 0 && u < 128 * 128) lwh[u] = (_Float16)lw[u];
}

// ---------------------------------------------------------------------------
// K1: heterogeneous grid — counting blocks (0..127) + MFMA node tiles.
//   Counting (round-7): global-atomic rank. Block b owns edges
//   [b*6250, (b+1)*6250); rank[e] = atomicAdd(&deg[r],1). Reads the
//   receiver array ONCE (was 4x under quartering), writes no histogram,
//   uses no LDS -> kernel LDS drops 25KB -> 8KB (node-path occupancy up).
//   ~16 atomics/address over a 200KB L2-resident array; hidden under the
//   1563 node blocks' MFMA work.
//   Node path: unchanged verified form (32 nodes x 128 outs, 4 waves,
//   wave 0 computes as/ar side-product; h unified rows h[node][128]).
// ---------------------------------------------------------------------------
__global__ __launch_bounds__(256) void node_count_kernel(
    const float* __restrict__ x, const _Float16* __restrict__ lwh,
    const float* __restrict__ lb, const _Float16* __restrict__ w2h,
    const float* __restrict__ b2, const int* __restrict__ adj,
    __half* __restrict__ h, float* __restrict__ as4, float* __restrict__ ar4,
    int* __restrict__ deg, unsigned short* __restrict__ rank)
{
    __shared__ __align__(16) unsigned char xs[32 * 256];  // 8 KB

    if (blockIdx.x < NCNT) {
        // ---- counting path: contiguous range, global-atomic rank ----
        const int e0 = blockIdx.x * EPC, e1 = e0 + EPC;
        for (int base = e0 + threadIdx.x; base < e1; base += 8 * 256) {
            int rs[8];
            #pragma unroll
            for (int u = 0; u < 8; u++) {
                int e = base + u * 256;
                rs[u] = (e < e1) ? adj[N_EDGES + e] : -1;
            }
            #pragma unroll
            for (int u = 0; u < 8; u++) {
                int e = base + u * 256;
                if (rs[u] >= 0) {
                    int old = atomicAdd(&deg[rs[u]], 1);
                    rank[e] = (unsigned short)old;
                }
            }
        }
        return;
    }

    // ---- node MFMA path ----
    const int tx = threadIdx.x;
    const int nb = (blockIdx.x - NCNT) * 32;

    // stage x tile as fp16, swizzled (byte ^= (node&7)<<4)
    #pragma unroll
    for (int it = 0; it < 2; it++) {
        int cc = it * 256 + tx;           // 16B chunk id (512 total)
        int node = cc >> 4, kc = cc & 15;
        int gn = nb + node;
        f16x8 v;
        if (gn < N_NODES) {
            const float4* xr = (const float4*)(x + (size_t)gn * 128 + kc * 8);
            float4 p = xr[0], qq = xr[1];
            v[0] = (_Float16)p.x;  v[1] = (_Float16)p.y;
            v[2] = (_Float16)p.z;  v[3] = (_Float16)p.w;
            v[4] = (_Float16)qq.x; v[5] = (_Float16)qq.y;
            v[6] = (_Float16)qq.z; v[7] = (_Float16)qq.w;
        } else {
            #pragma unroll
            for (int e = 0; e < 8; e++) v[e] = (_Float16)0.0f;
        }
        int byte = node * 256 + ((kc * 16) ^ ((node & 7) << 4));
        *(f16x8*)(xs + byte) = v;
    }
    __syncthreads();

    const int wave = tx >> 6, lane = tx & 63;
    const int l15 = lane & 15, lg = lane >> 4;

    // A fragments: lw[out][k]
    f16x8 afr[2][4];
    #pragma unroll
    for (int m = 0; m < 2; m++) {
        int out = wave * 32 + m * 16 + l15;
        const f16x8* ar8 = (const f16x8*)(lwh + (size_t)out * 128);
        #pragma unroll
        for (int kk = 0; kk < 4; kk++)
            afr[m][kk] = ar8[kk * 4 + lg];
    }
    // side-product A fragments (wave 0 only uses them)
    f16x8 a6[4];
    {
        const f16x8* w8 = (const f16x8*)(w2h + (size_t)l15 * 128);
        #pragma unroll
        for (int kk = 0; kk < 4; kk++) a6[kk] = w8[kk * 4 + lg];
    }

    f32x4 acc[2][2], acc6[2];
    #pragma unroll
    for (int m = 0; m < 2; m++)
        #pragma unroll
        for (int n = 0; n < 2; n++)
            acc[m][n] = (f32x4){0.f, 0.f, 0.f, 0.f};
    #pragma unroll
    for (int n = 0; n < 2; n++) acc6[n] = (f32x4){0.f, 0.f, 0.f, 0.f};

    #pragma unroll
    for (int kk = 0; kk < 4; kk++) {
        f16x8 bfr[2];
        #pragma unroll
        for (int n = 0; n < 2; n++) {
            int node = n * 16 + l15;
            int byte = node * 256 + ((kk * 64 + lg * 16) ^ ((node & 7) << 4));
            bfr[n] = *(const f16x8*)(xs + byte);
        }
        #pragma unroll
        for (int m = 0; m < 2; m++)
            #pragma unroll
            for (int n = 0; n < 2; n++)
                acc[m][n] = __builtin_amdgcn_mfma_f32_16x16x32_f16(
                    afr[m][kk], bfr[n], acc[m][n], 0, 0, 0);
        if (wave == 0) {
            #pragma unroll
            for (int n = 0; n < 2; n++)
                acc6[n] = __builtin_amdgcn_mfma_f32_16x16x32_f16(
                    a6[kk], bfr[n], acc6[n], 0, 0, 0);
        }
    }

    // epilogue: h (unified fp16 rows, 8B store per lane per fragment)
    #pragma unroll
    for (int n = 0; n < 2; n++) {
        int gn = nb + n * 16 + l15;
        if (gn >= N_NODES) continue;
        #pragma unroll
        for (int m = 0; m < 2; m++) {
            int outb = wave * 32 + m * 16 + lg * 4;
            float4 lbv = *(const float4*)&lb[outb];
            __half2 p0 = __floats2half2_rn(acc[m][n].x + lbv.x, acc[m][n].y + lbv.y);
            __half2 p1 = __floats2half2_rn(acc[m][n].z + lbv.z, acc[m][n].w + lbv.w);
            int2 st;
            st.x = *(int*)&p0;
            st.y = *(int*)&p1;
            *(int2*)&h[(size_t)gn * 128 + outb] = st;
        }
    }

    // epilogue: as/ar (wave 0; lg=0 rows 0-3 -> as, lg=1 rows 4-7 -> ar)
    if (wave == 0 && lg < 2) {
        float b0, bx, by;
        if (lg == 0) { b0 = b2[0]; bx = b2[1]; by = b2[2]; }
        else         { b0 = b2[3]; bx = b2[4]; by = b2[5]; }
        #pragma unroll
        for (int n = 0; n < 2; n++) {
            int gn = nb + n * 16 + l15;
            if (gn >= N_NODES) continue;
            float4 v = make_float4(acc6[n].x + b0, acc6[n].y + bx,
                                   acc6[n].z + by, 0.0f);
            if (lg == 0) *(float4*)&as4[(size_t)gn * 4] = v;
            else         *(float4*)&ar4[(size_t)gn * 4] = v;
        }
    }
}

// ---------------------------------------------------------------------------
// K2: single-dispatch device-wide prefix sum over deg[] -> start[].
// Same proven two-level agent-scope handshake; the 32-slice hist loop and
// offs16 write are gone (global-atomic rank made them unnecessary).
// ---------------------------------------------------------------------------
__global__ __launch_bounds__(256) void scan_kernel(
    const int* __restrict__ deg, int* __restrict__ start,
    int* __restrict__ psum, int* __restrict__ poffs, int* __restrict__ sync)
{
    const int t = threadIdx.x, b = blockIdx.x;
    const int i = b * 256 + t;
    const int tot = (i < N_NODES) ? deg[i] : 0;
    __shared__ int shm[256];
    shm[t] = tot;
    __syncthreads();
    #pragma unroll
    for (int off = 1; off < 256; off <<= 1) {
        int u = (t >= off) ? shm[t - off] : 0;
        __syncthreads();
        shm[t] += u;
        __syncthreads();
    }
    const int incl = shm[t];
    if (t == 255)
        __hip_atomic_store(&psum[b], incl, __ATOMIC_RELAXED,
                           __HIP_MEMORY_SCOPE_AGENT);
    __syncthreads();
    if (t == 0)
        __hip_atomic_fetch_add(&sync[0], 1, __ATOMIC_RELEASE,
                               __HIP_MEMORY_SCOPE_AGENT);

    if (b == 0) {
        if (t == 0)
            while (__hip_atomic_load(&sync[0], __ATOMIC_ACQUIRE,
                                     __HIP_MEMORY_SCOPE_AGENT) < SCAN_NB) {}
        __syncthreads();
        int pv = (t < SCAN_NB)
               ? __hip_atomic_load(&psum[t], __ATOMIC_RELAXED,
                                   __HIP_MEMORY_SCOPE_AGENT)
               : 0;
        shm[t] = pv;
        __syncthreads();
        #pragma unroll
        for (int off = 1; off < 256; off <<= 1) {
            int u = (t >= off) ? shm[t - off] : 0;
            __syncthreads();
            shm[t] += u;
            __syncthreads();
        }
        if (t < SCAN_NB)
            __hip_atomic_store(&poffs[t], shm[t] - pv, __ATOMIC_RELAXED,
                               __HIP_MEMORY_SCOPE_AGENT);
        __syncthreads();
        if (t == 0)
            __hip_atomic_store(&sync[1], 1, __ATOMIC_RELEASE,
                               __HIP_MEMORY_SCOPE_AGENT);
    }

    if (t == 0)
        while (__hip_atomic_load(&sync[1], __ATOMIC_ACQUIRE,
                                 __HIP_MEMORY_SCOPE_AGENT) == 0) {}
    __syncthreads();
    const int base = __hip_atomic_load(&poffs[b], __ATOMIC_RELAXED,
                                       __HIP_MEMORY_SCOPE_AGENT);
    if (i < N_NODES) start[i] = base + incl - tot;
    if (i == N_NODES - 1) start[N_NODES] = base + incl;
}

// ---------------------------------------------------------------------------
// K3: CSR fill — atomic-free: pos = start[r] + rank[e] (global rank).
// ---------------------------------------------------------------------------
__global__ __launch_bounds__(256) void fill_kernel(
    const int* __restrict__ adj, const int* __restrict__ start,
    const unsigned short* __restrict__ rank,
    unsigned short* __restrict__ srcs)
{
    int e = blockIdx.x * 512 + threadIdx.x;
    #pragma unroll
    for (int u = 0; u < 2; u++, e += 256) {
        if (e < N_EDGES) {
            int r = adj[N_EDGES + e];
            int pos = start[r] + (int)rank[e];
            srcs[pos] = (unsigned short)adj[e];
        }
    }
}

// ---------------------------------------------------------------------------
// K4: fused segment-softmax + aggregation + silu. Wave-per-node.
// Exact round-2/6 form (45.6 µs; pinned at the random-256B gather fabric
// roofline ~3.5 TB/s — confirmed congestion-bound by round-5 A/B).
// ---------------------------------------------------------------------------
__global__ __launch_bounds__(256) void agg_kernel(
    const int* __restrict__ start, const unsigned short* __restrict__ srcs,
    const float4* __restrict__ as4, const float* __restrict__ ar4,
    const __half* __restrict__ h, float* __restrict__ out)
{
    const int wave = threadIdx.x >> 6;
    const int lane = threadIdx.x & 63;
    const int n = blockIdx.x * 4 + wave;
    if (n >= N_NODES) return;
    const int s0 = start[n], s1 = start[n + 1];
    const int deg = s1 - s0;

    __shared__ float sh_c[4][64];
    __shared__ int   sh_s[4][64];

    const float4 cr = *(const float4*)&ar4[(size_t)n * 4];
    const int quar = lane >> 4, l15 = lane & 15;
    const int4* hq = (const int4*)h;       // 16 chunks of 16B per 256B row
    float a0 = 0.f, a1 = 0.f, a2 = 0.f, a3 = 0.f;
    float a4 = 0.f, a5 = 0.f, a6 = 0.f, a7 = 0.f;

    if (deg <= 64) {
        float e0 = 0.f, e1 = 0.f, e2 = 0.f;
        int s = 0;
        if (lane < deg) {
            s = srcs[s0 + lane];
            float4 a = as4[s];
            e0 = __expf(a.x + cr.x);
            e1 = __expf(a.y + cr.y);
            e2 = __expf(a.z + cr.z);
        }
        float p0 = e0, p1 = e1, p2 = e2;
        #pragma unroll
        for (int off = 32; off >= 1; off >>= 1) {
            p0 += __shfl_xor(p0, off);
            p1 += __shfl_xor(p1, off);
            p2 += __shfl_xor(p2, off);
        }
        const float i0 = (1.0f / 3.0f) / fmaxf(p0, 1e-30f);
        const float i1 = (1.0f / 3.0f) / fmaxf(p1, 1e-30f);
        const float i2 = (1.0f / 3.0f) / fmaxf(p2, 1e-30f);
        if (lane < deg) {
            sh_s[wave][lane] = s;
            sh_c[wave][lane] = e0 * i0 + e1 * i1 + e2 * i2;
        } else if (lane < deg + 3) {       // up to 3 sentinels for 4-step
            sh_s[wave][lane] = 0;
            sh_c[wave][lane] = 0.0f;
        }
        // wave-lockstep: no barrier (wave-private LDS region)
        #pragma unroll 2
        for (int j = 0; j < deg; j += 4) {
            int jj = j + quar;
            float c = sh_c[wave][jj];
            int sj = sh_s[wave][jj];
            int4 hv = hq[(size_t)sj * 16 + l15];
            float2 f0 = __half22float2(*(const __half2*)&hv.x);
            float2 f1 = __half22float2(*(const __half2*)&hv.y);
            float2 f2 = __half22float2(*(const __half2*)&hv.z);
            float2 f3 = __half22float2(*(const __half2*)&hv.w);
            a0 = fmaf(f0.x, c, a0); a1 = fmaf(f0.y, c, a1);
            a2 = fmaf(f1.x, c, a2); a3 = fmaf(f1.y, c, a3);
            a4 = fmaf(f2.x, c, a4); a5 = fmaf(f2.y, c, a5);
            a6 = fmaf(f3.x, c, a6); a7 = fmaf(f3.y, c, a7);
        }
    } else {
        float p0 = 0.f, p1 = 0.f, p2 = 0.f;
        for (int k = s0 + lane; k < s1; k += 64) {
            float4 a = as4[srcs[k]];
            p0 += __expf(a.x + cr.x);
            p1 += __expf(a.y + cr.y);
            p2 += __expf(a.z + cr.z);
        }
        #pragma unroll
        for (int off = 32; off >= 1; off >>= 1) {
            p0 += __shfl_xor(p0, off);
            p1 += __shfl_xor(p1, off);
            p2 += __shfl_xor(p2, off);
        }
        const float i0 = (1.0f / 3.0f) / fmaxf(p0, 1e-30f);
        const float i1 = (1.0f / 3.0f) / fmaxf(p1, 1e-30f);
        const float i2 = (1.0f / 3.0f) / fmaxf(p2, 1e-30f);

        for (int cb = s0; cb < s1; cb += 64) {
            int cnt = min(64, s1 - cb);
            if (lane < cnt) {
                int s = srcs[cb + lane];
                float4 a = as4[s];
                sh_s[wave][lane] = s;
                sh_c[wave][lane] = __expf(a.x + cr.x) * i0
                                 + __expf(a.y + cr.y) * i1
                                 + __expf(a.z + cr.z) * i2;
            } else if (lane < cnt + 3) {   // sentinels (only when cnt < 64)
                sh_s[wave][lane] = 0;
                sh_c[wave][lane] = 0.0f;
            }
            #pragma unroll 2
            for (int j = 0; j < cnt; j += 4) {
                int jj = j + quar;
                float c = sh_c[wave][jj];
                int sj = sh_s[wave][jj];
                int4 hv = hq[(size_t)sj * 16 + l15];
                float2 f0 = __half22float2(*(const __half2*)&hv.x);
                float2 f1 = __half22float2(*(const __half2*)&hv.y);
                float2 f2 = __half22float2(*(const __half2*)&hv.z);
                float2 f3 = __half22float2(*(const __half2*)&hv.w);
                a0 = fmaf(f0.x, c, a0); a1 = fmaf(f0.y, c, a1);
                a2 = fmaf(f1.x, c, a2); a3 = fmaf(f1.y, c, a3);
                a4 = fmaf(f2.x, c, a4); a5 = fmaf(f2.y, c, a5);
                a6 = fmaf(f3.x, c, a6); a7 = fmaf(f3.y, c, a7);
            }
        }
    }

    // combine quarters: XOR 16 then 32 gives every quarter the full sum
    a0 += __shfl_xor(a0, 16); a0 += __shfl_xor(a0, 32);
    a1 += __shfl_xor(a1, 16); a1 += __shfl_xor(a1, 32);
    a2 += __shfl_xor(a2, 16); a2 += __shfl_xor(a2, 32);
    a3 += __shfl_xor(a3, 16); a3 += __shfl_xor(a3, 32);
    a4 += __shfl_xor(a4, 16); a4 += __shfl_xor(a4, 32);
    a5 += __shfl_xor(a5, 16); a5 += __shfl_xor(a5, 32);
    a6 += __shfl_xor(a6, 16); a6 += __shfl_xor(a6, 32);
    a7 += __shfl_xor(a7, 16); a7 += __shfl_xor(a7, 32);

    if (quar == 0) {
        float4 o0, o1;
        o0.x = a0 / (1.0f + __expf(-a0));
        o0.y = a1 / (1.0f + __expf(-a1));
        o0.z = a2 / (1.0f + __expf(-a2));
        o0.w = a3 / (1.0f + __expf(-a3));
        o1.x = a4 / (1.0f + __expf(-a4));
        o1.y = a5 / (1.0f + __expf(-a5));
        o1.z = a6 / (1.0f + __expf(-a6));
        o1.w = a7 / (1.0f + __expf(-a7));
        *(float4*)&out[(size_t)n * 128 + l15 * 8] = o0;
        *(float4*)&out[(size_t)n * 128 + l15 * 8 + 4] = o1;
    }
}

// ---------------------------------------------------------------------------
extern "C" void kernel_launch(void* const* d_in, const int* in_sizes, int n_in,
                              void* d_out, int out_size, void* d_ws, size_t ws_size,
                              hipStream_t stream)
{
    const float* x  = (const float*)d_in[0];
    const int*   adj= (const int*)  d_in[1];
    const float* Wq = (const float*)d_in[2];
    const float* bq = (const float*)d_in[3];
    const float* aw = (const float*)d_in[4];
    const float* ab = (const float*)d_in[5];
    const float* lw = (const float*)d_in[6];
    const float* lb = (const float*)d_in[7];
    float* out = (float*)d_out;

    // workspace layout (16B-aligned arrays first)
    _Float16* w2h = (_Float16*)d_ws;                       // 2048 halves
    float* b2     = (float*)(w2h + 2048);                  // 8
    _Float16* lwh = (_Float16*)(b2 + 8);                   // 16384 halves
    float* as4    = (float*)(lwh + 16384);                 // N*4
    float* ar4    = as4 + (size_t)N_NODES * 4;             // N*4
    __half* h     = (__half*)(ar4 + (size_t)N_NODES * 4);  // N*128 halves
    int* start    = (int*)(h + (size_t)N_NODES * 128);     // N+1
    int* sync     = start + (N_NODES + 1);                 // 8 (zeroed by K0)
    int* deg      = sync + 8;                              // N (zeroed by K0)
    unsigned short* rank = (unsigned short*)(deg + N_NODES);   // E
    unsigned short* srcs = rank + N_EDGES;                 // E
    int* psum     = (int*)(srcs + N_EDGES);                // 256
    int* poffs    = psum + 256;                            // 256

    weights_kernel<<<72, 256, 0, stream>>>(Wq, bq, aw, ab, lw, w2h, b2, lwh,
                                           sync, deg);

    node_count_kernel<<<NCNT + NODE_NB, 256, 0, stream>>>(
        x, lwh, lb, w2h, b2, adj, h, as4, ar4, deg, rank);

    scan_kernel<<<SCAN_NB, 256, 0, stream>>>(deg, start, psum, poffs, sync);

    fill_kernel<<<(N_EDGES + 511) / 512, 256, 0, stream>>>(
        adj, start, rank, srcs);

    agg_kernel<<<(N_NODES + 3) / 4, 256, 0, stream>>>(
        start, srcs, (const float4*)as4, ar4, h, out);
}

// Round 8
// 112.350 us; speedup vs baseline: 1.0495x; 1.0495x over previous
//
#include <hip/hip_runtime.h>
#include <hip/hip_fp16.h>
#include <math.h>

#define N_NODES 50000
#define N_EDGES 800000
#define IN_F 128
#define OUT_F 128
#define NH 3
#define SCAN_NB ((N_NODES + 255) / 256)   // 196
#define NODE_NB ((N_NODES + 31) / 32)     // 1563
#define NBH 32                            // histogram edge slices
#define EPB (N_EDGES / NBH)               // 25000 edges per slice
#define QNODES (N_NODES / 4)              // 12500 nodes per quarter
#define CQ_BLOCKS (NBH * 4)               // 128 counting blocks

typedef __attribute__((ext_vector_type(8))) _Float16 f16x8;
typedef __attribute__((ext_vector_type(4))) float f32x4;

// ---------------------------------------------------------------------------
// K0: weight preprocessing + zeroing the scan handshake cells (validated in
// rounds 5-7; replaces the hipMemsetAsync dispatch).
// ---------------------------------------------------------------------------
__global__ __launch_bounds__(256) void weights_kernel(
    const float* __restrict__ Wq, const float* __restrict__ bq,
    const float* __restrict__ aw, const float* __restrict__ ab,
    const float* __restrict__ lw,
    _Float16* __restrict__ w2h, float* __restrict__ b2,
    _Float16* __restrict__ lwh, int* __restrict__ sync)
{
    int t = blockIdx.x * 256 + threadIdx.x;
    if (blockIdx.x == 0 && threadIdx.x < 8) sync[threadIdx.x] = 0;
    if (t < 16 * 128) {
        int prow = t >> 7;
        int i    = t & 127;
        int r = -1;                       // logical row 0..5
        if (prow < 3) r = prow;
        else if (prow >= 4 && prow < 7) r = prow - 1;
        if (r < 0) {
            w2h[prow * 128 + i] = (_Float16)0.0f;
        } else {
            int hh  = (r < 3) ? r : r - 3;
            int off = (r < 3) ? 0 : 24;
            const float* awr = aw + hh * 48 + off;
            float acc = 0.0f;
            #pragma unroll
            for (int q = 0; q < 24; q++) acc += awr[q] * Wq[q * 128 + i];
            w2h[prow * 128 + i] = (_Float16)acc;
            if (i == 0) {
                float b = 0.0f;
                #pragma unroll
                for (int q = 0; q < 24; q++) b += awr[q] * bq[q];
                if (r >= 3) b += ab[hh];
                b2[r] = b;
            }
        }
    }
    int u = t - 16 * 128;
    if (u >= 0 && u < 128 * 128) lwh[u] = (_Float16)lw[u];
}

// ---------------------------------------------------------------------------
// K1: heterogeneous grid — counting blocks (0..127) + MFMA node tiles.
//   Counting: slice c = b>>2 (25000 edges), quarter q = b&3 (12500 nodes),
//   25 KB LDS histogram; LDS atomicAdd return = per-(slice,node) rank.
//   (Round-7's global-atomic variant regressed to 45 µs — TCC atomic
//   serialization; LDS histogram is the verified fast form.)
//   Node: 32 nodes x 128 outs, 4 waves; wave 0 computes as/ar side-product.
//   h in unified row layout h[node][128].
// ---------------------------------------------------------------------------
__global__ __launch_bounds__(256) void node_count_kernel(
    const float* __restrict__ x, const _Float16* __restrict__ lwh,
    const float* __restrict__ lb, const _Float16* __restrict__ w2h,
    const float* __restrict__ b2, const int* __restrict__ adj,
    __half* __restrict__ h, float* __restrict__ as4, float* __restrict__ ar4,
    unsigned int* __restrict__ hist, unsigned short* __restrict__ rank)
{
    __shared__ __align__(16) unsigned int shmem[QNODES / 2];  // 25 KB

    if (blockIdx.x < CQ_BLOCKS) {
        // ---- counting path ----
        unsigned int* cnt = shmem;
        for (int i = threadIdx.x; i < QNODES / 2; i += 256) cnt[i] = 0;
        __syncthreads();
        const int c = blockIdx.x >> 2, q = blockIdx.x & 3;
        const int nlo = q * QNODES;
        const int e0 = c * EPB, e1 = e0 + EPB;
        for (int base = e0 + threadIdx.x; base < e1; base += 8 * 256) {
            int rs[8];
            #pragma unroll
            for (int u = 0; u < 8; u++) {
                int e = base + u * 256;
                rs[u] = (e < e1) ? adj[N_EDGES + e] : -1;
            }
            #pragma unroll
            for (int u = 0; u < 8; u++) {
                int e = base + u * 256;
                int lr = rs[u] - nlo;
                if ((unsigned)lr < (unsigned)QNODES) {
                    int sh = (lr & 1) * 16;
                    unsigned int old = atomicAdd(&cnt[lr >> 1], 1u << sh);
                    rank[e] = (unsigned short)(old >> sh);
                }
            }
        }
        __syncthreads();
        unsigned int* hb = hist + (size_t)c * (N_NODES / 2) + q * (QNODES / 2);
        for (int i = threadIdx.x; i < QNODES / 2; i += 256)
            hb[i] = cnt[i];
        return;
    }

    // ---- node MFMA path ----
    unsigned char* xs = (unsigned char*)shmem;   // 8 KB of the 25 KB
    const int tx = threadIdx.x;
    const int nb = (blockIdx.x - CQ_BLOCKS) * 32;

    // stage x tile as fp16, swizzled (byte ^= (node&7)<<4)
    #pragma unroll
    for (int it = 0; it < 2; it++) {
        int cc = it * 256 + tx;           // 16B chunk id (512 total)
        int node = cc >> 4, kc = cc & 15;
        int gn = nb + node;
        f16x8 v;
        if (gn < N_NODES) {
            const float4* xr = (const float4*)(x + (size_t)gn * 128 + kc * 8);
            float4 p = xr[0], qq = xr[1];
            v[0] = (_Float16)p.x;  v[1] = (_Float16)p.y;
            v[2] = (_Float16)p.z;  v[3] = (_Float16)p.w;
            v[4] = (_Float16)qq.x; v[5] = (_Float16)qq.y;
            v[6] = (_Float16)qq.z; v[7] = (_Float16)qq.w;
        } else {
            #pragma unroll
            for (int e = 0; e < 8; e++) v[e] = (_Float16)0.0f;
        }
        int byte = node * 256 + ((kc * 16) ^ ((node & 7) << 4));
        *(f16x8*)(xs + byte) = v;
    }
    __syncthreads();

    const int wave = tx >> 6, lane = tx & 63;
    const int l15 = lane & 15, lg = lane >> 4;

    // A fragments: lw[out][k]
    f16x8 afr[2][4];
    #pragma unroll
    for (int m = 0; m < 2; m++) {
        int out = wave * 32 + m * 16 + l15;
        const f16x8* ar8 = (const f16x8*)(lwh + (size_t)out * 128);
        #pragma unroll
        for (int kk = 0; kk < 4; kk++)
            afr[m][kk] = ar8[kk * 4 + lg];
    }
    // side-product A fragments (wave 0 only uses them)
    f16x8 a6[4];
    {
        const f16x8* w8 = (const f16x8*)(w2h + (size_t)l15 * 128);
        #pragma unroll
        for (int kk = 0; kk < 4; kk++) a6[kk] = w8[kk * 4 + lg];
    }

    f32x4 acc[2][2], acc6[2];
    #pragma unroll
    for (int m = 0; m < 2; m++)
        #pragma unroll
        for (int n = 0; n < 2; n++)
            acc[m][n] = (f32x4){0.f, 0.f, 0.f, 0.f};
    #pragma unroll
    for (int n = 0; n < 2; n++) acc6[n] = (f32x4){0.f, 0.f, 0.f, 0.f};

    #pragma unroll
    for (int kk = 0; kk < 4; kk++) {
        f16x8 bfr[2];
        #pragma unroll
        for (int n = 0; n < 2; n++) {
            int node = n * 16 + l15;
            int byte = node * 256 + ((kk * 64 + lg * 16) ^ ((node & 7) << 4));
            bfr[n] = *(const f16x8*)(xs + byte);
        }
        #pragma unroll
        for (int m = 0; m < 2; m++)
            #pragma unroll
            for (int n = 0; n < 2; n++)
                acc[m][n] = __builtin_amdgcn_mfma_f32_16x16x32_f16(
                    afr[m][kk], bfr[n], acc[m][n], 0, 0, 0);
        if (wave == 0) {
            #pragma unroll
            for (int n = 0; n < 2; n++)
                acc6[n] = __builtin_amdgcn_mfma_f32_16x16x32_f16(
                    a6[kk], bfr[n], acc6[n], 0, 0, 0);
        }
    }

    // epilogue: h (unified fp16 rows, 8B store per lane per fragment)
    #pragma unroll
    for (int n = 0; n < 2; n++) {
        int gn = nb + n * 16 + l15;
        if (gn >= N_NODES) continue;
        #pragma unroll
        for (int m = 0; m < 2; m++) {
            int outb = wave * 32 + m * 16 + lg * 4;
            float4 lbv = *(const float4*)&lb[outb];
            __half2 p0 = __floats2half2_rn(acc[m][n].x + lbv.x, acc[m][n].y + lbv.y);
            __half2 p1 = __floats2half2_rn(acc[m][n].z + lbv.z, acc[m][n].w + lbv.w);
            int2 st;
            st.x = *(int*)&p0;
            st.y = *(int*)&p1;
            *(int2*)&h[(size_t)gn * 128 + outb] = st;
        }
    }

    // epilogue: as/ar (wave 0; lg=0 rows 0-3 -> as, lg=1 rows 4-7 -> ar)
    if (wave == 0 && lg < 2) {
        float b0, bx, by;
        if (lg == 0) { b0 = b2[0]; bx = b2[1]; by = b2[2]; }
        else         { b0 = b2[3]; bx = b2[4]; by = b2[5]; }
        #pragma unroll
        for (int n = 0; n < 2; n++) {
            int gn = nb + n * 16 + l15;
            if (gn >= N_NODES) continue;
            float4 v = make_float4(acc6[n].x + b0, acc6[n].y + bx,
                                   acc6[n].z + by, 0.0f);
            if (lg == 0) *(float4*)&as4[(size_t)gn * 4] = v;
            else         *(float4*)&ar4[(size_t)gn * 4] = v;
        }
    }
}

// ---------------------------------------------------------------------------
// K2: single-dispatch device-wide scan. Round-8 tweak: hist values cached
// in registers on the first pass (hv[32]) — the offs16 loop no longer
// re-reads the 3.2 MB hist array (one pass instead of two).
// ---------------------------------------------------------------------------
__global__ __launch_bounds__(256) void scan_kernel(
    const unsigned int* __restrict__ hist, int* __restrict__ start,
    unsigned short* __restrict__ offs16,
    int* __restrict__ psum, int* __restrict__ poffs, int* __restrict__ sync)
{
    const int t = threadIdx.x, b = blockIdx.x;
    const int i = b * 256 + t;
    const int w = i >> 1, sh = (i & 1) * 16;
    unsigned short hv[NBH];
    int tot = 0;
    if (i < N_NODES) {
        #pragma unroll
        for (int c = 0; c < NBH; c++) {
            hv[c] = (unsigned short)
                ((hist[(size_t)c * (N_NODES / 2) + w] >> sh) & 0xffff);
            tot += hv[c];
        }
    }
    __shared__ int shm[256];
    shm[t] = tot;
    __syncthreads();
    #pragma unroll
    for (int off = 1; off < 256; off <<= 1) {
        int u = (t >= off) ? shm[t - off] : 0;
        __syncthreads();
        shm[t] += u;
        __syncthreads();
    }
    const int incl = shm[t];
    if (t == 255)
        __hip_atomic_store(&psum[b], incl, __ATOMIC_RELAXED,
                           __HIP_MEMORY_SCOPE_AGENT);
    __syncthreads();
    if (t == 0)
        __hip_atomic_fetch_add(&sync[0], 1, __ATOMIC_RELEASE,
                               __HIP_MEMORY_SCOPE_AGENT);

    if (b == 0) {
        if (t == 0)
            while (__hip_atomic_load(&sync[0], __ATOMIC_ACQUIRE,
                                     __HIP_MEMORY_SCOPE_AGENT) < SCAN_NB) {}
        __syncthreads();
        int pv = (t < SCAN_NB)
               ? __hip_atomic_load(&psum[t], __ATOMIC_RELAXED,
                                   __HIP_MEMORY_SCOPE_AGENT)
               : 0;
        shm[t] = pv;
        __syncthreads();
        #pragma unroll
        for (int off = 1; off < 256; off <<= 1) {
            int u = (t >= off) ? shm[t - off] : 0;
            __syncthreads();
            shm[t] += u;
            __syncthreads();
        }
        if (t < SCAN_NB)
            __hip_atomic_store(&poffs[t], shm[t] - pv, __ATOMIC_RELAXED,
                               __HIP_MEMORY_SCOPE_AGENT);
        __syncthreads();
        if (t == 0)
            __hip_atomic_store(&sync[1], 1, __ATOMIC_RELEASE,
                               __HIP_MEMORY_SCOPE_AGENT);
    }

    if (t == 0)
        while (__hip_atomic_load(&sync[1], __ATOMIC_ACQUIRE,
                                 __HIP_MEMORY_SCOPE_AGENT) == 0) {}
    __syncthreads();
    const int base = __hip_atomic_load(&poffs[b], __ATOMIC_RELAXED,
                                       __HIP_MEMORY_SCOPE_AGENT);
    if (i < N_NODES) {
        start[i] = base + incl - tot;
        int acc = 0;
        #pragma unroll
        for (int c = 0; c < NBH; c++) {
            offs16[(size_t)c * N_NODES + i] = (unsigned short)acc;
            acc += hv[c];
        }
    }
    if (i == N_NODES - 1) start[N_NODES] = base + incl;
}

// ---------------------------------------------------------------------------
// K3: CSR fill — fully atomic-free. (verified round-0/2/6 form)
// ---------------------------------------------------------------------------
__global__ __launch_bounds__(256) void fill_kernel(
    const int* __restrict__ adj, const int* __restrict__ start,
    const unsigned short* __restrict__ offs16,
    const unsigned short* __restrict__ rank,
    unsigned short* __restrict__ srcs)
{
    int e = blockIdx.x * 512 + threadIdx.x;
    #pragma unroll
    for (int u = 0; u < 2; u++, e += 256) {
        if (e < N_EDGES) {
            int r = adj[N_EDGES + e];
            int cb = e / EPB;
            int pos = start[r] + (int)offs16[(size_t)cb * N_NODES + r]
                    + (int)rank[e];
            srcs[pos] = (unsigned short)adj[e];
        }
    }
}

// ---------------------------------------------------------------------------
// K4: fused segment-softmax + aggregation + silu. Wave-per-node.
// Exact round-2/6 form (45.6 µs; pinned at the random-256B gather fabric
// roofline ~3.5 TB/s — confirmed congestion-bound by round-5 concurrency
// A/B; sliced alternatives are VALU-bound at the same ~45 µs).
// ---------------------------------------------------------------------------
__global__ __launch_bounds__(256) void agg_kernel(
    const int* __restrict__ start, const unsigned short* __restrict__ srcs,
    const float4* __restrict__ as4, const float* __restrict__ ar4,
    const __half* __restrict__ h, float* __restrict__ out)
{
    const int wave = threadIdx.x >> 6;
    const int lane = threadIdx.x & 63;
    const int n = blockIdx.x * 4 + wave;
    if (n >= N_NODES) return;
    const int s0 = start[n], s1 = start[n + 1];
    const int deg = s1 - s0;

    __shared__ float sh_c[4][64];
    __shared__ int   sh_s[4][64];

    const float4 cr = *(const float4*)&ar4[(size_t)n * 4];
    const int quar = lane >> 4, l15 = lane & 15;
    const int4* hq = (const int4*)h;       // 16 chunks of 16B per 256B row
    float a0 = 0.f, a1 = 0.f, a2 = 0.f, a3 = 0.f;
    float a4 = 0.f, a5 = 0.f, a6 = 0.f, a7 = 0.f;

    if (deg <= 64) {
        float e0 = 0.f, e1 = 0.f, e2 = 0.f;
        int s = 0;
        if (lane < deg) {
            s = srcs[s0 + lane];
            float4 a = as4[s];
            e0 = __expf(a.x + cr.x);
            e1 = __expf(a.y + cr.y);
            e2 = __expf(a.z + cr.z);
        }
        float p0 = e0, p1 = e1, p2 = e2;
        #pragma unroll
        for (int off = 32; off >= 1; off >>= 1) {
            p0 += __shfl_xor(p0, off);
            p1 += __shfl_xor(p1, off);
            p2 += __shfl_xor(p2, off);
        }
        const float i0 = (1.0f / 3.0f) / fmaxf(p0, 1e-30f);
        const float i1 = (1.0f / 3.0f) / fmaxf(p1, 1e-30f);
        const float i2 = (1.0f / 3.0f) / fmaxf(p2, 1e-30f);
        if (lane < deg) {
            sh_s[wave][lane] = s;
            sh_c[wave][lane] = e0 * i0 + e1 * i1 + e2 * i2;
        } else if (lane < deg + 3) {       // up to 3 sentinels for 4-step
            sh_s[wave][lane] = 0;
            sh_c[wave][lane] = 0.0f;
        }
        // wave-lockstep: no barrier (wave-private LDS region)
        #pragma unroll 2
        for (int j = 0; j < deg; j += 4) {
            int jj = j + quar;
            float c = sh_c[wave][jj];
            int sj = sh_s[wave][jj];
            int4 hv = hq[(size_t)sj * 16 + l15];
            float2 f0 = __half22float2(*(const __half2*)&hv.x);
            float2 f1 = __half22float2(*(const __half2*)&hv.y);
            float2 f2 = __half22float2(*(const __half2*)&hv.z);
            float2 f3 = __half22float2(*(const __half2*)&hv.w);
            a0 = fmaf(f0.x, c, a0); a1 = fmaf(f0.y, c, a1);
            a2 = fmaf(f1.x, c, a2); a3 = fmaf(f1.y, c, a3);
            a4 = fmaf(f2.x, c, a4); a5 = fmaf(f2.y, c, a5);
            a6 = fmaf(f3.x, c, a6); a7 = fmaf(f3.y, c, a7);
        }
    } else {
        float p0 = 0.f, p1 = 0.f, p2 = 0.f;
        for (int k = s0 + lane; k < s1; k += 64) {
            float4 a = as4[srcs[k]];
            p0 += __expf(a.x + cr.x);
            p1 += __expf(a.y + cr.y);
            p2 += __expf(a.z + cr.z);
        }
        #pragma unroll
        for (int off = 32; off >= 1; off >>= 1) {
            p0 += __shfl_xor(p0, off);
            p1 += __shfl_xor(p1, off);
            p2 += __shfl_xor(p2, off);
        }
        const float i0 = (1.0f / 3.0f) / fmaxf(p0, 1e-30f);
        const float i1 = (1.0f / 3.0f) / fmaxf(p1, 1e-30f);
        const float i2 = (1.0f / 3.0f) / fmaxf(p2, 1e-30f);

        for (int cb = s0; cb < s1; cb += 64) {
            int cnt = min(64, s1 - cb);
            if (lane < cnt) {
                int s = srcs[cb + lane];
                float4 a = as4[s];
                sh_s[wave][lane] = s;
                sh_c[wave][lane] = __expf(a.x + cr.x) * i0
                                 + __expf(a.y + cr.y) * i1
                                 + __expf(a.z + cr.z) * i2;
            } else if (lane < cnt + 3) {   // sentinels (only when cnt < 64)
                sh_s[wave][lane] = 0;
                sh_c[wave][lane] = 0.0f;
            }
            #pragma unroll 2
            for (int j = 0; j < cnt; j += 4) {
                int jj = j + quar;
                float c = sh_c[wave][jj];
                int sj = sh_s[wave][jj];
                int4 hv = hq[(size_t)sj * 16 + l15];
                float2 f0 = __half22float2(*(const __half2*)&hv.x);
                float2 f1 = __half22float2(*(const __half2*)&hv.y);
                float2 f2 = __half22float2(*(const __half2*)&hv.z);
                float2 f3 = __half22float2(*(const __half2*)&hv.w);
                a0 = fmaf(f0.x, c, a0); a1 = fmaf(f0.y, c, a1);
                a2 = fmaf(f1.x, c, a2); a3 = fmaf(f1.y, c, a3);
                a4 = fmaf(f2.x, c, a4); a5 = fmaf(f2.y, c, a5);
                a6 = fmaf(f3.x, c, a6); a7 = fmaf(f3.y, c, a7);
            }
        }
    }

    // combine quarters: XOR 16 then 32 gives every quarter the full sum
    a0 += __shfl_xor(a0, 16); a0 += __shfl_xor(a0, 32);
    a1 += __shfl_xor(a1, 16); a1 += __shfl_xor(a1, 32);
    a2 += __shfl_xor(a2, 16); a2 += __shfl_xor(a2, 32);
    a3 += __shfl_xor(a3, 16); a3 += __shfl_xor(a3, 32);
    a4 += __shfl_xor(a4, 16); a4 += __shfl_xor(a4, 32);
    a5 += __shfl_xor(a5, 16); a5 += __shfl_xor(a5, 32);
    a6 += __shfl_xor(a6, 16); a6 += __shfl_xor(a6, 32);
    a7 += __shfl_xor(a7, 16); a7 += __shfl_xor(a7, 32);

    if (quar == 0) {
        float4 o0, o1;
        o0.x = a0 / (1.0f + __expf(-a0));
        o0.y = a1 / (1.0f + __expf(-a1));
        o0.z = a2 / (1.0f + __expf(-a2));
        o0.w = a3 / (1.0f + __expf(-a3));
        o1.x = a4 / (1.0f + __expf(-a4));
        o1.y = a5 / (1.0f + __expf(-a5));
        o1.z = a6 / (1.0f + __expf(-a6));
        o1.w = a7 / (1.0f + __expf(-a7));
        *(float4*)&out[(size_t)n * 128 + l15 * 8] = o0;
        *(float4*)&out[(size_t)n * 128 + l15 * 8 + 4] = o1;
    }
}

// ---------------------------------------------------------------------------
extern "C" void kernel_launch(void* const* d_in, const int* in_sizes, int n_in,
                              void* d_out, int out_size, void* d_ws, size_t ws_size,
                              hipStream_t stream)
{
    const float* x  = (const float*)d_in[0];
    const int*   adj= (const int*)  d_in[1];
    const float* Wq = (const float*)d_in[2];
    const float* bq = (const float*)d_in[3];
    const float* aw = (const float*)d_in[4];
    const float* ab = (const float*)d_in[5];
    const float* lw = (const float*)d_in[6];
    const float* lb = (const float*)d_in[7];
    float* out = (float*)d_out;

    // workspace layout (16B-aligned arrays first)
    _Float16* w2h = (_Float16*)d_ws;                       // 2048 halves
    float* b2     = (float*)(w2h + 2048);                  // 8
    _Float16* lwh = (_Float16*)(b2 + 8);                   // 16384 halves
    float* as4    = (float*)(lwh + 16384);                 // N*4
    float* ar4    = as4 + (size_t)N_NODES * 4;             // N*4
    __half* h     = (__half*)(ar4 + (size_t)N_NODES * 4);  // N*128 halves
    int* start    = (int*)(h + (size_t)N_NODES * 128);     // N+1
    int* sync     = start + (N_NODES + 1);                 // 8 (zeroed by K0)
    unsigned int* hist = (unsigned int*)(sync + 8);        // NBH * N/2
    unsigned short* offs16 = (unsigned short*)(hist + (size_t)NBH * (N_NODES / 2)); // NBH*N
    unsigned short* rank   = offs16 + (size_t)NBH * N_NODES; // E
    unsigned short* srcs   = rank + N_EDGES;               // E
    int* psum     = (int*)(srcs + N_EDGES);                // 256
    int* poffs    = psum + 256;                            // 256

    weights_kernel<<<72, 256, 0, stream>>>(Wq, bq, aw, ab, lw, w2h, b2, lwh,
                                           sync);

    node_count_kernel<<<CQ_BLOCKS + NODE_NB, 256, 0, stream>>>(
        x, lwh, lb, w2h, b2, adj, h, as4, ar4, hist, rank);

    scan_kernel<<<SCAN_NB, 256, 0, stream>>>(hist, start, offs16,
                                             psum, poffs, sync);

    fill_kernel<<<(N_EDGES + 511) / 512, 256, 0, stream>>>(
        adj, start, offs16, rank, srcs);

    agg_kernel<<<(N_NODES + 3) / 4, 256, 0, stream>>>(
        start, srcs, (const float4*)as4, ar4, h, out);
}